// Round 4
// baseline (277.605 us; speedup 1.0000x reference)
//
#include <hip/hip_runtime.h>

// ---------- types ----------
typedef _Float16 f16;
typedef _Float16 f16x4 __attribute__((ext_vector_type(4)));
typedef _Float16 f16x8 __attribute__((ext_vector_type(8)));
typedef float    f32x4 __attribute__((ext_vector_type(4)));

#define N_ROWS 100000
#define RT 1563           // 1563 * 64 = 100032 padded rows
#define LSH1 136          // h1 LDS tile stride (f16): 68 dw, odd*4 -> 2-way max
#define LSH2 72           // h2 LDS tile stride (f16): 36 dw

// ws layout (bytes): weights only
#define W1T_OFF 0
#define W1T_BYTES (256 * 256 * 2)
#define W2T_OFF W1T_BYTES

// ---------- prep: combined, transposed f16 weights (one launch) ----------
__global__ void prep_w(const float* __restrict__ wz1, const float* __restrict__ wh1,
                       const float* __restrict__ wz2, const float* __restrict__ wh2,
                       f16* __restrict__ W1T, f16* __restrict__ W2T) {
    const int b = blockIdx.x;
    if (b < 256) {                                 // W1: 65536 elems
        int idx = b * 256 + threadIdx.x;
        int k = idx >> 8, c = idx & 255;
        const float* w = (c < 128) ? wz1 : wh1;
        int cc = c & 127;
        W1T[c * 256 + k] = (f16)(w[k * 128 + cc] + w[384 * 128 + k * 128 + cc]);
    } else {                                       // W2: 16384 elems
        int idx = (b - 256) * 256 + threadIdx.x;
        int k = idx >> 7, c = idx & 127;
        const float* w = (c < 64) ? wz2 : wh2;
        int cc = c & 63;
        W2T[c * 128 + k] = (f16)(w[k * 64 + cc] + w[192 * 64 + k * 64 + cc]);
    }
}

// ---------- fused: 64 rows/block through L1 -> L2 -> lin, barrier-free K-loops ----------
__global__ __launch_bounds__(256, 2) void fused(
    const float* __restrict__ x,
    const f16* __restrict__ W1T, const f16* __restrict__ W2T,
    const float* __restrict__ bz1, const float* __restrict__ bh1,
    const float* __restrict__ bz2, const float* __restrict__ bh2,
    const float* __restrict__ wl1, const float* __restrict__ bl1,
    const float* __restrict__ wl2, const float* __restrict__ bl2,
    float* __restrict__ out)
{
    __shared__ __align__(16) f16 h1s[64 * LSH1];   // 17.4 KB
    __shared__ __align__(16) f16 h2s[64 * LSH2];   //  9.2 KB

    const int tid = threadIdx.x, lane = tid & 63, wave = tid >> 6;
    const int ln = lane & 15, quad = lane >> 4;
    const int rh = wave >> 1, jh = wave & 1;
    const int r0 = blockIdx.x * 64;
    const int jgq = quad << 2;

    // ================= Phase 1: h1 = gates(X @ W1) =================
    // Swapped: A = W1T cols (m), B = X rows (n). Wave (rh,jh): rows 32rh..+32
    // (nt 0,1); comb cols: z = 64jh+16mt'+ln (mt 0..3), h = 128+64jh+16mt'+ln (mt 4..7).
    const float* xbase[2];
#pragma unroll
    for (int nt = 0; nt < 2; ++nt) {
        int gr = r0 + 32 * rh + 16 * nt + ln;
        if (gr >= N_ROWS) gr = N_ROWS - 1;
        xbase[nt] = x + (size_t)gr * 256 + quad * 8;
    }
    const f16* wbase[8];
#pragma unroll
    for (int mt = 0; mt < 8; ++mt) {
        const int col = ((mt & 3) << 4) + (jh << 6) + ((mt >> 2) << 7) + ln;
        wbase[mt] = W1T + col * 256 + quad * 8;
    }

    f32x4 acc[8][2];
#pragma unroll
    for (int a = 0; a < 8; ++a)
#pragma unroll
        for (int b = 0; b < 2; ++b) acc[a][b] = (f32x4){0.f, 0.f, 0.f, 0.f};

#define P1_LOAD(DXA, DXB, DW, KC)                                \
    _Pragma("unroll") for (int nt = 0; nt < 2; ++nt) {           \
        DXA[nt] = *(const float4*)(xbase[nt] + (KC) * 32);       \
        DXB[nt] = *(const float4*)(xbase[nt] + (KC) * 32 + 4);   \
    }                                                            \
    _Pragma("unroll") for (int mt = 0; mt < 8; ++mt)             \
        DW[mt] = *(const f16x8*)(wbase[mt] + (KC) * 32);

    float4 cxa[2], cxb[2]; f16x8 cw[8];
    P1_LOAD(cxa, cxb, cw, 0)

#pragma unroll
    for (int kc = 0; kc < 8; ++kc) {
        float4 nxa[2], nxb[2]; f16x8 nw[8];
        if (kc < 7) { P1_LOAD(nxa, nxb, nw, kc + 1) }   // in flight during MFMAs
        f16x8 bf[2];
#pragma unroll
        for (int nt = 0; nt < 2; ++nt)
            bf[nt] = (f16x8){(f16)cxa[nt].x, (f16)cxa[nt].y, (f16)cxa[nt].z, (f16)cxa[nt].w,
                             (f16)cxb[nt].x, (f16)cxb[nt].y, (f16)cxb[nt].z, (f16)cxb[nt].w};
#pragma unroll
        for (int mt = 0; mt < 8; ++mt)
#pragma unroll
            for (int nt = 0; nt < 2; ++nt)
                acc[mt][nt] = __builtin_amdgcn_mfma_f32_16x16x32_f16(cw[mt], bf[nt], acc[mt][nt], 0, 0, 0);
#pragma unroll
        for (int nt = 0; nt < 2; ++nt) { cxa[nt] = nxa[nt]; cxb[nt] = nxb[nt]; }
#pragma unroll
        for (int mt = 0; mt < 8; ++mt) cw[mt] = nw[mt];
    }
#undef P1_LOAD

    // P1 epilogue: D col(ln)=X row, row(4quad+i)=comb col. z=acc[mtp], h=acc[mtp+4].
#pragma unroll
    for (int mtp = 0; mtp < 4; ++mtp) {
        const int jg0 = (jh << 6) + (mtp << 4) + jgq;
        const float4 zb = *(const float4*)(bz1 + jg0);
        const float4 hb = *(const float4*)(bh1 + jg0);
        const float zbv[4] = {zb.x, zb.y, zb.z, zb.w};
        const float hbv[4] = {hb.x, hb.y, hb.z, hb.w};
#pragma unroll
        for (int nt = 0; nt < 2; ++nt) {
            const int row = 32 * rh + 16 * nt + ln;
            f16x4 pk;
#pragma unroll
            for (int i = 0; i < 4; ++i) {
                float zp = acc[mtp][nt][i] + zbv[i];
                float hp = acc[mtp + 4][nt][i] + hbv[i];
                float ex = __expf(2.0f * hp);
                float th = 1.0f - 2.0f / (ex + 1.0f);      // tanh(hp)
                float sg = 1.0f / (1.0f + __expf(zp));     // 1 - sigmoid(zp)
                pk[i] = (f16)fmaxf(th * sg, 0.0f);
            }
            *(f16x4*)&h1s[row * LSH1 + jg0] = pk;
        }
    }
    __syncthreads();

    // ================= Phase 2: h2 = gates(h1 @ W2) =================
    // A = W2T cols (m): z = 32jh+16mt'+ln (mt 0,1), h = 64+32jh+16mt'+ln (mt 2,3).
    const f16* w2base[4];
#pragma unroll
    for (int mt = 0; mt < 4; ++mt) {
        const int col = ((mt & 1) << 4) + (jh << 5) + ((mt >> 1) << 6) + ln;
        w2base[mt] = W2T + col * 128 + quad * 8;
    }
    f32x4 acc2[4][2];
#pragma unroll
    for (int a = 0; a < 4; ++a)
#pragma unroll
        for (int b = 0; b < 2; ++b) acc2[a][b] = (f32x4){0.f, 0.f, 0.f, 0.f};

#pragma unroll
    for (int kc = 0; kc < 4; ++kc) {
        f16x8 bf[2];
#pragma unroll
        for (int nt = 0; nt < 2; ++nt)
            bf[nt] = *(const f16x8*)&h1s[(32 * rh + 16 * nt + ln) * LSH1 + kc * 32 + quad * 8];
#pragma unroll
        for (int mt = 0; mt < 4; ++mt) {
            f16x8 af = *(const f16x8*)(w2base[mt] + kc * 32);
#pragma unroll
            for (int nt = 0; nt < 2; ++nt)
                acc2[mt][nt] = __builtin_amdgcn_mfma_f32_16x16x32_f16(af, bf[nt], acc2[mt][nt], 0, 0, 0);
        }
    }

#pragma unroll
    for (int mtp = 0; mtp < 2; ++mtp) {
        const int jg0 = (jh << 5) + (mtp << 4) + jgq;
        const float4 zb = *(const float4*)(bz2 + jg0);
        const float4 hb = *(const float4*)(bh2 + jg0);
        const float zbv[4] = {zb.x, zb.y, zb.z, zb.w};
        const float hbv[4] = {hb.x, hb.y, hb.z, hb.w};
#pragma unroll
        for (int nt = 0; nt < 2; ++nt) {
            const int row = 32 * rh + 16 * nt + ln;
            f16x4 pk;
#pragma unroll
            for (int i = 0; i < 4; ++i) {
                float zp = acc2[mtp][nt][i] + zbv[i];
                float hp = acc2[mtp + 2][nt][i] + hbv[i];
                float ex = __expf(2.0f * hp);
                float th = 1.0f - 2.0f / (ex + 1.0f);
                float sg = 1.0f / (1.0f + __expf(zp));
                pk[i] = (f16)fmaxf(th * sg, 0.0f);
            }
            *(f16x4*)&h2s[row * LSH2 + jg0] = pk;
        }
    }
    __syncthreads();

    // ================= Phase 3: out = relu(h2 @ wl1 + bl1) @ wl2 + bl2 =================
    // Non-swapped: A = h2 rows 16*wave..+16 (m=ln), B = wl1 (n=ln col).
    const float blv  = bl1[ln];
    const float wlv  = wl2[ln];
    const float bl2v = bl2[0];
    f16x8 bfr[2];
#pragma unroll
    for (int kc = 0; kc < 2; ++kc)
#pragma unroll
        for (int j = 0; j < 8; ++j)
            bfr[kc][j] = (f16)wl1[(kc * 32 + quad * 8 + j) * 16 + ln];

    f32x4 acc3 = (f32x4){0.f, 0.f, 0.f, 0.f};
#pragma unroll
    for (int kc = 0; kc < 2; ++kc) {
        f16x8 af = *(const f16x8*)&h2s[(16 * wave + ln) * LSH2 + kc * 32 + quad * 8];
        acc3 = __builtin_amdgcn_mfma_f32_16x16x32_f16(af, bfr[kc], acc3, 0, 0, 0);
    }

#pragma unroll
    for (int i = 0; i < 4; ++i) {
        float v = fmaxf(acc3[i] + blv, 0.0f) * wlv;
        v += __shfl_xor(v, 1);
        v += __shfl_xor(v, 2);
        v += __shfl_xor(v, 4);
        v += __shfl_xor(v, 8);
        if (ln == 0) {
            const int row = r0 + 16 * wave + (quad << 2) + i;
            if (row < N_ROWS) out[row] = v + bl2v;
        }
    }
}

// ---------- launch ----------
extern "C" void kernel_launch(void* const* d_in, const int* in_sizes, int n_in,
                              void* d_out, int out_size, void* d_ws, size_t ws_size,
                              hipStream_t stream) {
    const float* x   = (const float*)d_in[0];
    const float* wz1 = (const float*)d_in[3];
    const float* bz1 = (const float*)d_in[4];
    const float* wh1 = (const float*)d_in[7];
    const float* bh1 = (const float*)d_in[8];
    const float* wz2 = (const float*)d_in[9];
    const float* bz2 = (const float*)d_in[10];
    const float* wh2 = (const float*)d_in[13];
    const float* bh2 = (const float*)d_in[14];
    const float* wl1 = (const float*)d_in[15];
    const float* bl1 = (const float*)d_in[16];
    const float* wl2 = (const float*)d_in[17];
    const float* bl2 = (const float*)d_in[18];

    char* ws = (char*)d_ws;
    f16* W1T = (f16*)(ws + W1T_OFF);
    f16* W2T = (f16*)(ws + W2T_OFF);
    float* out = (float*)d_out;

    prep_w<<<320, 256, 0, stream>>>(wz1, wh1, wz2, wh2, W1T, W2T);
    fused<<<RT, 256, 0, stream>>>(x, W1T, W2T, bz1, bh1, bz2, bh2,
                                  wl1, bl1, wl2, bl2, out);
}